// Round 5
// baseline (54.710 us; speedup 1.0000x reference)
//
#include <hip/hip_runtime.h>
#include <math.h>

#define NB 8
#define NN 2048
#define ND 128
#define NHID 256
#define PROJ 64
#define TH_IN 387
#define TH_HID 128

// ---------------- Kernel A: seed/argmax, kq = Wk^T (Wq @ x_seed), theta MLP ----
__global__ __launch_bounds__(1024) void seed_theta_kernel(
    const float* __restrict__ x, const float* __restrict__ seed_ctx,
    const float* __restrict__ local_stats, const float* __restrict__ cmask,
    const float* __restrict__ Wq, const float* __restrict__ Wk,
    const float* __restrict__ W1, const float* __restrict__ b1,
    const float* __restrict__ W2, const float* __restrict__ b2,
    float* __restrict__ kq_ws, float* __restrict__ theta_ws,
    float* __restrict__ out_theta)
{
  const int b = blockIdx.x;
  const int t = threadIdx.x;
  const int wave = t >> 6, lane = t & 63;

  __shared__ float swv[16]; __shared__ int swi[16];
  __shared__ float sx[ND];
  __shared__ float sq[PROJ];
  __shared__ float tin[TH_IN];
  __shared__ float part[8][TH_HID];
  __shared__ float sred[TH_HID];
  __shared__ int s_seed;

  // ---- argmax(cluster_mask[b]) -> earliest index attaining max ----
  {
    float v0 = cmask[b*NN + t];
    float v1 = cmask[b*NN + t + 1024];
    float bv = v0; int bi = t;
    if (v1 > bv) { bv = v1; bi = t + 1024; }
    for (int off = 32; off; off >>= 1) {
      float ov = __shfl_xor(bv, off);
      int   oi = __shfl_xor(bi, off);
      if (ov > bv || (ov == bv && oi < bi)) { bv = ov; bi = oi; }
    }
    if (lane == 0) { swv[wave] = bv; swi[wave] = bi; }
  }
  __syncthreads();
  if (t == 0) {
    float bv = swv[0]; int bi = swi[0];
    #pragma unroll
    for (int w = 1; w < 16; ++w)
      if (swv[w] > bv || (swv[w] == bv && swi[w] < bi)) { bv = swv[w]; bi = swi[w]; }
    s_seed = bi;
  }
  __syncthreads();
  const int seed = s_seed;

  if (t < ND) sx[t] = x[((size_t)b*NN + seed)*ND + t];
  __syncthreads();

  // ---- q[h] = Wq[h,:] . sx : one h per (wave, j), lane-split + shfl reduce
  {
    const int h = wave*4;
    #pragma unroll
    for (int j = 0; j < 4; ++j) {
      float a = Wq[(h+j)*ND + lane] * sx[lane]
              + Wq[(h+j)*ND + 64 + lane] * sx[64 + lane];
      for (int off = 32; off; off >>= 1) a += __shfl_xor(a, off);
      if (lane == 0) sq[h+j] = a;
    }
  }
  __syncthreads();

  // ---- kq[d] = sum_h Wk[h,d]*q[h] : 8 h-chunks across threads (coalesced d)
  {
    const int c = t >> 7;
    const int d = t & 127;
    float acc = 0.f;
    #pragma unroll
    for (int j = 0; j < 8; ++j) acc += Wk[(c*8 + j)*ND + d] * sq[c*8 + j];
    part[c][d] = acc;
  }
  __syncthreads();
  if (t < ND) {
    float acc = 0.f;
    #pragma unroll
    for (int c = 0; c < 8; ++c) acc += part[c][t];
    kq_ws[b*ND + t] = acc;
  }

  // ---- theta head: Linear(387->128) -> ReLU -> Linear(128->1)
  if (t < ND + NHID) tin[t] = seed_ctx[b*(ND+NHID) + t];
  if (t >= ND + NHID && t < TH_IN) tin[t] = local_stats[b*3 + (t - (ND+NHID))];
  __syncthreads();
  {
    const int c = t >> 7;            // i-chunk 0..7 (~49 each)
    const int h = t & 127;
    const int i0 = c*49;
    const int i1 = (c == 7) ? TH_IN : i0 + 49;
    float acc = 0.f;
    for (int i = i0; i < i1; ++i) acc += tin[i] * W1[i*TH_HID + h];
    part[c][h] = acc;
  }
  __syncthreads();
  if (t < TH_HID) {
    float acc = b1[t];
    #pragma unroll
    for (int c = 0; c < 8; ++c) acc += part[c][t];
    acc = fmaxf(acc, 0.f);
    sred[t] = acc * W2[t];
  }
  __syncthreads();
  if (t < 64) {
    float v = sred[t] + sred[t + 64];
    for (int off = 32; off; off >>= 1) v += __shfl_xor(v, off);
    if (t == 0) {
      float th = v + b2[0];
      theta_ws[b] = th;
      out_theta[b] = th;
    }
  }
}

// ---- Kernel B: 8 adj rows/block (1 per wave); writes p/hard + block partial --
__global__ __launch_bounds__(512) void row_kernel(
    const float* __restrict__ x, const float* __restrict__ adj,
    const float* __restrict__ cmask, const float* __restrict__ candm,
    const float* __restrict__ kq_ws, const float* __restrict__ theta_ws,
    float* __restrict__ out_hard, float* __restrict__ out_p,
    float* __restrict__ pv1, int* __restrict__ pi1,
    float* __restrict__ pv2, int* __restrict__ pi2, int* __restrict__ pcnt)
{
  const int t = threadIdx.x;
  const int wave = t >> 6, lane = t & 63;
  const int row0 = blockIdx.x * 8;
  const int b = row0 >> 11;               // 2048 rows per batch
  __shared__ float sCm[NN];
  __shared__ float sKq[ND];
  __shared__ float sTheta;
  __shared__ float rv[8]; __shared__ int rc[8];

  const float4* cm4 = (const float4*)(cmask + b*NN);
  ((float4*)sCm)[t] = cm4[t];             // 512 threads x 16B = 8KB
  if (t < ND) sKq[t] = kq_ws[b*ND + t];
  if (t == 0) sTheta = theta_ws[b];
  __syncthreads();

  const int row = row0 + wave;            // global row == b*NN + n
  const int n = row & (NN - 1);
  const float4* a4 = (const float4*)(adj + (size_t)row * NN);
  float deg = 0.f, e2c = 0.f;
  #pragma unroll
  for (int k = 0; k < 8; ++k) {
    const int idx = k*64 + lane;
    float4 a = a4[idx];
    float4 c = ((float4*)sCm)[idx];
    deg += a.x + a.y + a.z + a.w;
    e2c += a.x*c.x + a.y*c.y + a.z*c.z + a.w*c.w;
  }
  const float2* x2 = (const float2*)(x + (size_t)row * ND);
  float2 xv = x2[lane];
  float sc = xv.x * sKq[2*lane] + xv.y * sKq[2*lane + 1];

  for (int off = 32; off; off >>= 1) {
    deg += __shfl_xor(deg, off);
    e2c += __shfl_xor(e2c, off);
    sc  += __shfl_xor(sc, off);
  }

  if (lane == 0) {
    float dd = fmaxf(deg, 1.0f);
    float cand = sc * 0.125f + 0.2f * (e2c / dd);   // /sqrt(64) == *0.125
    float p = 1.0f / (1.0f + expf(-(cand - sTheta)));  // TAU == 1
    p *= candm[row];
    out_p[row] = p;
    out_hard[row] = (p > 0.5f) ? 1.0f : 0.0f;
    rv[wave] = p; rc[wave] = (p > 0.5f) ? 1 : 0;
  }
  __syncthreads();
  if (t == 0) {
    // ascending wave order == ascending n; strict '>' keeps lowest index on ties
    float V1 = -1e30f, V2 = -1e30f; int I1 = 0, I2 = 0, cnt = 0;
    #pragma unroll
    for (int w = 0; w < 8; ++w) {
      float v = rv[w]; int idx = (row0 & (NN-1)) + w;
      cnt += rc[w];
      if (v > V1)      { V2=V1; I2=I1; V1=v; I1=idx; }
      else if (v > V2) { V2=v;  I2=idx; }
    }
    pv1[blockIdx.x] = V1; pi1[blockIdx.x] = I1;
    pv2[blockIdx.x] = V2; pi2[blockIdx.x] = I2;
    pcnt[blockIdx.x] = cnt;
  }
}

// ---- Kernel C: merge 256 partials per batch, trim if count > 2 --------------
__global__ __launch_bounds__(256) void trim_kernel(
    const float* __restrict__ pv1, const int* __restrict__ pi1,
    const float* __restrict__ pv2, const int* __restrict__ pi2,
    const int* __restrict__ pcnt,
    float* __restrict__ out_hard, float* __restrict__ out_p)
{
  const int b = blockIdx.x;
  const int t = threadIdx.x;
  const int g = b*256 + t;
  __shared__ int scnt[256];
  __shared__ float sv1[256]; __shared__ int si1[256];
  __shared__ float sv2[256]; __shared__ int si2[256];
  __shared__ int s_trim, s_k1, s_k2;

  scnt[t] = pcnt[g];
  sv1[t] = pv1[g]; si1[t] = pi1[g];
  sv2[t] = pv2[g]; si2[t] = pi2[g];
  __syncthreads();
  // partial t covers strictly lower n than t+s; strict '>' keeps lowest index
  for (int s = 128; s > 0; s >>= 1) {
    if (t < s) {
      scnt[t] += scnt[t+s];
      float B1 = sv1[t+s]; int Bi1 = si1[t+s];
      float B2 = sv2[t+s]; int Bi2 = si2[t+s];
      float V1 = sv1[t], V2 = sv2[t]; int I1 = si1[t], I2 = si2[t];
      if (B1 > V1)      { V2=V1; I2=I1; V1=B1; I1=Bi1; }
      else if (B1 > V2) { V2=B1; I2=Bi1; }
      if (B2 > V1)      { V2=V1; I2=I1; V1=B2; I1=Bi2; }
      else if (B2 > V2) { V2=B2; I2=Bi2; }
      sv1[t]=V1; si1[t]=I1; sv2[t]=V2; si2[t]=I2;
    }
    __syncthreads();
  }
  if (t == 0) {
    s_trim = (scnt[0] > 2) ? 1 : 0;   // over = count - (CLUSTER_SIZE_MAX-1) > 0
    s_k1 = si1[0]; s_k2 = si2[0];
  }
  __syncthreads();
  if (s_trim) {
    float* p    = out_p    + b*NN;
    float* hard = out_hard + b*NN;
    #pragma unroll
    for (int j = 0; j < 8; ++j) {
      const int nidx = j*256 + t;
      if (nidx != s_k1 && nidx != s_k2) { p[nidx] = 0.f; hard[nidx] = 0.f; }
    }
  }
}

extern "C" void kernel_launch(void* const* d_in, const int* in_sizes, int n_in,
                              void* d_out, int out_size, void* d_ws, size_t ws_size,
                              hipStream_t stream) {
  const float* x          = (const float*)d_in[0];
  const float* adj        = (const float*)d_in[1];
  const float* seed_ctx   = (const float*)d_in[2];
  const float* local_st   = (const float*)d_in[3];
  const float* cmask      = (const float*)d_in[4];
  const float* candm      = (const float*)d_in[5];
  const float* Wq         = (const float*)d_in[6];
  const float* Wk         = (const float*)d_in[7];
  const float* W1         = (const float*)d_in[8];
  const float* b1         = (const float*)d_in[9];
  const float* W2         = (const float*)d_in[10];
  const float* b2         = (const float*)d_in[11];

  float* out      = (float*)d_out;
  float* out_hard = out;                // [B,N]
  float* out_p    = out + NB*NN;        // [B,N]
  float* out_th   = out + 2*NB*NN;      // [B]

  const int NBLK = NB*NN/8;             // 2048 row-blocks
  float* ws       = (float*)d_ws;
  float* kq_ws    = ws;                 // 1024
  float* theta_ws = ws + NB*ND;         // 8
  float* pv1      = ws + NB*ND + NB;          // 2048
  float* pv2      = pv1 + NBLK;               // 2048
  int*   pi1      = (int*)(pv2 + NBLK);       // 2048
  int*   pi2      = pi1 + NBLK;               // 2048
  int*   pcnt     = pi2 + NBLK;               // 2048

  seed_theta_kernel<<<NB, 1024, 0, stream>>>(x, seed_ctx, local_st, cmask,
                                             Wq, Wk, W1, b1, W2, b2,
                                             kq_ws, theta_ws, out_th);
  row_kernel<<<NBLK, 512, 0, stream>>>(x, adj, cmask, candm, kq_ws, theta_ws,
                                       out_hard, out_p, pv1, pi1, pv2, pi2, pcnt);
  trim_kernel<<<NB, 256, 0, stream>>>(pv1, pi1, pv2, pi2, pcnt,
                                      out_hard, out_p);
}

// Round 6
// 37.865 us; speedup vs baseline: 1.4449x; 1.4449x over previous
//
#include <hip/hip_runtime.h>
#include <math.h>

#define NB 8
#define NN 2048
#define ND 128
#define NHID 256
#define PROJ 64
#define TH_IN 387
#define TH_HID 128

// -------- Kernel A: argmax seed, kq, theta MLP, cluster-index compaction -----
__global__ __launch_bounds__(1024) void seed_theta_kernel(
    const float* __restrict__ x, const float* __restrict__ seed_ctx,
    const float* __restrict__ local_stats, const float* __restrict__ cmask,
    const float* __restrict__ Wq, const float* __restrict__ Wk,
    const float* __restrict__ W1, const float* __restrict__ b1,
    const float* __restrict__ W2, const float* __restrict__ b2,
    float* __restrict__ kq_ws, float* __restrict__ theta_ws,
    int* __restrict__ cidx, float* __restrict__ cval, int* __restrict__ ccnt,
    float* __restrict__ out_theta)
{
  const int b = blockIdx.x;
  const int t = threadIdx.x;
  const int wave = t >> 6, lane = t & 63;

  __shared__ float swv[16]; __shared__ int swi[16];
  __shared__ float sx[ND];
  __shared__ float sq[PROJ];
  __shared__ float tin[TH_IN];
  __shared__ float part[8][TH_HID];
  __shared__ float sred[TH_HID];
  __shared__ int s_seed, s_cnt;

  if (t == 0) s_cnt = 0;

  // ---- load cmask (2 per thread), wave-reduce argmax (earliest index) ----
  const float c0 = cmask[b*NN + t];
  const float c1 = cmask[b*NN + t + 1024];
  {
    float bv = c0; int bi = t;
    if (c1 > bv) { bv = c1; bi = t + 1024; }
    for (int off = 32; off; off >>= 1) {
      float ov = __shfl_xor(bv, off);
      int   oi = __shfl_xor(bi, off);
      if (ov > bv || (ov == bv && oi < bi)) { bv = ov; bi = oi; }
    }
    if (lane == 0) { swv[wave] = bv; swi[wave] = bi; }
  }
  __syncthreads();   // also makes s_cnt=0 visible

  // ---- compact nonzero cluster members (order-free; 0/1 sums are exact) ----
  if (c0 != 0.f) { int s = atomicAdd(&s_cnt, 1); cidx[b*NN+s] = t;        cval[b*NN+s] = c0; }
  if (c1 != 0.f) { int s = atomicAdd(&s_cnt, 1); cidx[b*NN+s] = t + 1024; cval[b*NN+s] = c1; }

  if (t == 0) {
    float bv = swv[0]; int bi = swi[0];
    #pragma unroll
    for (int w = 1; w < 16; ++w)
      if (swv[w] > bv || (swv[w] == bv && swi[w] < bi)) { bv = swv[w]; bi = swi[w]; }
    s_seed = bi;
  }
  __syncthreads();   // atomics done; s_seed visible
  if (t == 0) ccnt[b] = s_cnt;
  const int seed = s_seed;

  if (t < ND) sx[t] = x[((size_t)b*NN + seed)*ND + t];
  __syncthreads();

  // ---- q[h] = Wq[h,:] . sx ----
  {
    const int h = wave*4;
    #pragma unroll
    for (int j = 0; j < 4; ++j) {
      float a = Wq[(h+j)*ND + lane] * sx[lane]
              + Wq[(h+j)*ND + 64 + lane] * sx[64 + lane];
      for (int off = 32; off; off >>= 1) a += __shfl_xor(a, off);
      if (lane == 0) sq[h+j] = a;
    }
  }
  __syncthreads();

  // ---- kq[d] = sum_h Wk[h,d]*q[h] ----
  {
    const int c = t >> 7;
    const int d = t & 127;
    float acc = 0.f;
    #pragma unroll
    for (int j = 0; j < 8; ++j) acc += Wk[(c*8 + j)*ND + d] * sq[c*8 + j];
    part[c][d] = acc;
  }
  __syncthreads();
  if (t < ND) {
    float acc = 0.f;
    #pragma unroll
    for (int c = 0; c < 8; ++c) acc += part[c][t];
    kq_ws[b*ND + t] = acc;
  }

  // ---- theta head: Linear(387->128) -> ReLU -> Linear(128->1) ----
  if (t < ND + NHID) tin[t] = seed_ctx[b*(ND+NHID) + t];
  if (t >= ND + NHID && t < TH_IN) tin[t] = local_stats[b*3 + (t - (ND+NHID))];
  __syncthreads();
  {
    const int c = t >> 7;
    const int h = t & 127;
    const int i0 = c*49;
    const int i1 = (c == 7) ? TH_IN : i0 + 49;
    float acc = 0.f;
    for (int i = i0; i < i1; ++i) acc += tin[i] * W1[i*TH_HID + h];
    part[c][h] = acc;
  }
  __syncthreads();
  if (t < TH_HID) {
    float acc = b1[t];
    #pragma unroll
    for (int c = 0; c < 8; ++c) acc += part[c][t];
    acc = fmaxf(acc, 0.f);
    sred[t] = acc * W2[t];
  }
  __syncthreads();
  if (t < 64) {
    float v = sred[t] + sred[t + 64];
    for (int off = 32; off; off >>= 1) v += __shfl_xor(v, off);
    if (t == 0) {
      float th = v + b2[0];
      theta_ws[b] = th;
      out_theta[b] = th;
    }
  }
}

// ---- Kernel B: sparse e2c gather; full row read ONLY where e2c != 0 ---------
// One wave per row, 8 rows/block. e2c = sum_k adj[row, cidx_k]*cval_k is an
// exact small-integer sum (adj,cmask in {0,1}), order-independent. deg only
// influences the output when e2c != 0 (else term is exactly +0.0).
__global__ __launch_bounds__(512) void row_kernel(
    const float* __restrict__ x, const float* __restrict__ adj,
    const float* __restrict__ candm,
    const float* __restrict__ kq_ws, const float* __restrict__ theta_ws,
    const int* __restrict__ cidx, const float* __restrict__ cval,
    const int* __restrict__ ccnt,
    float* __restrict__ out_hard, float* __restrict__ out_p,
    float* __restrict__ pv1, int* __restrict__ pi1,
    float* __restrict__ pv2, int* __restrict__ pi2, int* __restrict__ pcnt)
{
  const int t = threadIdx.x;
  const int wave = t >> 6, lane = t & 63;
  const int row0 = blockIdx.x * 8;
  const int b = row0 >> 11;               // 2048 rows per batch
  __shared__ float sKq[ND];
  __shared__ float sTheta; __shared__ int sK;
  __shared__ float rv[8]; __shared__ int rc[8];

  if (t < ND) sKq[t] = kq_ws[b*ND + t];
  if (t == 0) { sTheta = theta_ws[b]; sK = ccnt[b]; }
  __syncthreads();
  const int K = sK;

  const int row = row0 + wave;            // global row == b*NN + n
  const float* arow = adj + (size_t)row * NN;

  // score: x[row] . kq
  const float2* x2 = (const float2*)(x + (size_t)row * ND);
  float2 xv = x2[lane];
  float sc = xv.x * sKq[2*lane] + xv.y * sKq[2*lane + 1];

  // e2c: gather K entries (lane-parallel)
  float e2c = 0.f;
  for (int base = 0; base < K; base += 64) {
    const int k = base + lane;
    if (k < K) e2c += arow[cidx[b*NN + k]] * cval[b*NN + k];
  }

  for (int off = 32; off; off >>= 1) {
    sc  += __shfl_xor(sc, off);
    e2c += __shfl_xor(e2c, off);
  }

  float extra = 0.f;
  if (e2c != 0.f) {                       // wave-uniform branch (~4% of rows)
    const float4* a4 = (const float4*)arow;
    float deg = 0.f;
    #pragma unroll
    for (int k = 0; k < 8; ++k) {
      float4 a = a4[k*64 + lane];
      deg += a.x + a.y + a.z + a.w;
    }
    for (int off = 32; off; off >>= 1) deg += __shfl_xor(deg, off);
    extra = e2c / fmaxf(deg, 1.0f);
  }

  if (lane == 0) {
    float cand = sc * 0.125f + 0.2f * extra;        // /sqrt(64) == *0.125
    float p = 1.0f / (1.0f + expf(-(cand - sTheta)));  // TAU == 1
    p *= candm[row];
    out_p[row] = p;
    out_hard[row] = (p > 0.5f) ? 1.0f : 0.0f;
    rv[wave] = p; rc[wave] = (p > 0.5f) ? 1 : 0;
  }
  __syncthreads();
  if (t == 0) {
    float V1 = -1e30f, V2 = -1e30f; int I1 = 0, I2 = 0, cnt = 0;
    #pragma unroll
    for (int w = 0; w < 8; ++w) {       // ascending n; '>' keeps lowest on ties
      float v = rv[w]; int idx = (row0 & (NN-1)) + w;
      cnt += rc[w];
      if (v > V1)      { V2=V1; I2=I1; V1=v; I1=idx; }
      else if (v > V2) { V2=v;  I2=idx; }
    }
    pv1[blockIdx.x] = V1; pi1[blockIdx.x] = I1;
    pv2[blockIdx.x] = V2; pi2[blockIdx.x] = I2;
    pcnt[blockIdx.x] = cnt;
  }
}

// ---- Kernel C: merge 256 partials per batch, trim if count > 2 --------------
__global__ __launch_bounds__(256) void trim_kernel(
    const float* __restrict__ pv1, const int* __restrict__ pi1,
    const float* __restrict__ pv2, const int* __restrict__ pi2,
    const int* __restrict__ pcnt,
    float* __restrict__ out_hard, float* __restrict__ out_p)
{
  const int b = blockIdx.x;
  const int t = threadIdx.x;
  const int g = b*256 + t;
  __shared__ int scnt[256];
  __shared__ float sv1[256]; __shared__ int si1[256];
  __shared__ float sv2[256]; __shared__ int si2[256];
  __shared__ int s_trim, s_k1, s_k2;

  scnt[t] = pcnt[g];
  sv1[t] = pv1[g]; si1[t] = pi1[g];
  sv2[t] = pv2[g]; si2[t] = pi2[g];
  __syncthreads();
  for (int s = 128; s > 0; s >>= 1) {
    if (t < s) {
      scnt[t] += scnt[t+s];
      float B1 = sv1[t+s]; int Bi1 = si1[t+s];
      float B2 = sv2[t+s]; int Bi2 = si2[t+s];
      float V1 = sv1[t], V2 = sv2[t]; int I1 = si1[t], I2 = si2[t];
      if (B1 > V1)      { V2=V1; I2=I1; V1=B1; I1=Bi1; }
      else if (B1 > V2) { V2=B1; I2=Bi1; }
      if (B2 > V1)      { V2=V1; I2=I1; V1=B2; I1=Bi2; }
      else if (B2 > V2) { V2=B2; I2=Bi2; }
      sv1[t]=V1; si1[t]=I1; sv2[t]=V2; si2[t]=I2;
    }
    __syncthreads();
  }
  if (t == 0) {
    s_trim = (scnt[0] > 2) ? 1 : 0;   // over = count - (CLUSTER_SIZE_MAX-1) > 0
    s_k1 = si1[0]; s_k2 = si2[0];
  }
  __syncthreads();
  if (s_trim) {
    float* p    = out_p    + b*NN;
    float* hard = out_hard + b*NN;
    #pragma unroll
    for (int j = 0; j < 8; ++j) {
      const int nidx = j*256 + t;
      if (nidx != s_k1 && nidx != s_k2) { p[nidx] = 0.f; hard[nidx] = 0.f; }
    }
  }
}

extern "C" void kernel_launch(void* const* d_in, const int* in_sizes, int n_in,
                              void* d_out, int out_size, void* d_ws, size_t ws_size,
                              hipStream_t stream) {
  const float* x          = (const float*)d_in[0];
  const float* adj        = (const float*)d_in[1];
  const float* seed_ctx   = (const float*)d_in[2];
  const float* local_st   = (const float*)d_in[3];
  const float* cmask      = (const float*)d_in[4];
  const float* candm      = (const float*)d_in[5];
  const float* Wq         = (const float*)d_in[6];
  const float* Wk         = (const float*)d_in[7];
  const float* W1         = (const float*)d_in[8];
  const float* b1         = (const float*)d_in[9];
  const float* W2         = (const float*)d_in[10];
  const float* b2         = (const float*)d_in[11];

  float* out      = (float*)d_out;
  float* out_hard = out;                // [B,N]
  float* out_p    = out + NB*NN;        // [B,N]
  float* out_th   = out + 2*NB*NN;      // [B]

  const int NBLK = NB*NN/8;             // 2048 row-blocks
  float* ws       = (float*)d_ws;
  float* kq_ws    = ws;                       // 1024
  float* theta_ws = ws + NB*ND;               // 8
  float* pv1      = ws + NB*ND + NB;          // 2048
  float* pv2      = pv1 + NBLK;               // 2048
  int*   pi1      = (int*)(pv2 + NBLK);       // 2048
  int*   pi2      = pi1 + NBLK;               // 2048
  int*   pcnt     = pi2 + NBLK;               // 2048
  int*   cidx     = pcnt + NBLK;              // B*NN ints
  float* cval     = (float*)(cidx + NB*NN);   // B*NN floats
  int*   ccnt     = (int*)(cval + NB*NN);     // B ints

  seed_theta_kernel<<<NB, 1024, 0, stream>>>(x, seed_ctx, local_st, cmask,
                                             Wq, Wk, W1, b1, W2, b2,
                                             kq_ws, theta_ws,
                                             cidx, cval, ccnt, out_th);
  row_kernel<<<NBLK, 512, 0, stream>>>(x, adj, candm, kq_ws, theta_ws,
                                       cidx, cval, ccnt,
                                       out_hard, out_p, pv1, pi1, pv2, pi2, pcnt);
  trim_kernel<<<NB, 256, 0, stream>>>(pv1, pi1, pv2, pi2, pcnt,
                                      out_hard, out_p);
}

// Round 7
// 27.326 us; speedup vs baseline: 2.0022x; 1.3857x over previous
//
#include <hip/hip_runtime.h>
#include <math.h>

#define NB 8
#define NN 2048
#define ND 128
#define NHID 256
#define PROJ 64
#define TH_IN 387
#define TH_HID 128

// -------- Kernel A: argmax seed, kq, theta MLP, cluster-index compaction -----
__global__ __launch_bounds__(1024) void seed_theta_kernel(
    const float* __restrict__ x, const float* __restrict__ seed_ctx,
    const float* __restrict__ local_stats, const float* __restrict__ cmask,
    const float* __restrict__ Wq, const float* __restrict__ Wk,
    const float* __restrict__ W1, const float* __restrict__ b1,
    const float* __restrict__ W2, const float* __restrict__ b2,
    float* __restrict__ kq_ws, float* __restrict__ theta_ws,
    int* __restrict__ cidx, float* __restrict__ cval, int* __restrict__ ccnt,
    float* __restrict__ out_theta)
{
  const int b = blockIdx.x;
  const int t = threadIdx.x;
  const int wave = t >> 6, lane = t & 63;

  __shared__ float swv[16]; __shared__ int swi[16];
  __shared__ float sx[ND];
  __shared__ float sq[PROJ];
  __shared__ float tin[TH_IN];
  __shared__ float part[8][TH_HID];
  __shared__ float sred[TH_HID];
  __shared__ int s_seed, s_cnt;

  if (t == 0) s_cnt = 0;

  // ---- load cmask (2 per thread), wave-reduce argmax (earliest index) ----
  const float c0 = cmask[b*NN + t];
  const float c1 = cmask[b*NN + t + 1024];
  {
    float bv = c0; int bi = t;
    if (c1 > bv) { bv = c1; bi = t + 1024; }
    for (int off = 32; off; off >>= 1) {
      float ov = __shfl_xor(bv, off);
      int   oi = __shfl_xor(bi, off);
      if (ov > bv || (ov == bv && oi < bi)) { bv = ov; bi = oi; }
    }
    if (lane == 0) { swv[wave] = bv; swi[wave] = bi; }
  }
  __syncthreads();   // also makes s_cnt=0 visible

  // ---- compact nonzero cluster members (order-free; 0/1 sums are exact) ----
  if (c0 != 0.f) { int s = atomicAdd(&s_cnt, 1); cidx[b*NN+s] = t;        cval[b*NN+s] = c0; }
  if (c1 != 0.f) { int s = atomicAdd(&s_cnt, 1); cidx[b*NN+s] = t + 1024; cval[b*NN+s] = c1; }

  if (t == 0) {
    float bv = swv[0]; int bi = swi[0];
    #pragma unroll
    for (int w = 1; w < 16; ++w)
      if (swv[w] > bv || (swv[w] == bv && swi[w] < bi)) { bv = swv[w]; bi = swi[w]; }
    s_seed = bi;
  }
  __syncthreads();   // atomics done; s_seed visible
  if (t == 0) ccnt[b] = s_cnt;
  const int seed = s_seed;

  if (t < ND) sx[t] = x[((size_t)b*NN + seed)*ND + t];
  __syncthreads();

  // ---- q[h] = Wq[h,:] . sx ----
  {
    const int h = wave*4;
    #pragma unroll
    for (int j = 0; j < 4; ++j) {
      float a = Wq[(h+j)*ND + lane] * sx[lane]
              + Wq[(h+j)*ND + 64 + lane] * sx[64 + lane];
      for (int off = 32; off; off >>= 1) a += __shfl_xor(a, off);
      if (lane == 0) sq[h+j] = a;
    }
  }
  __syncthreads();

  // ---- kq[d] = sum_h Wk[h,d]*q[h] ----
  {
    const int c = t >> 7;
    const int d = t & 127;
    float acc = 0.f;
    #pragma unroll
    for (int j = 0; j < 8; ++j) acc += Wk[(c*8 + j)*ND + d] * sq[c*8 + j];
    part[c][d] = acc;
  }
  __syncthreads();
  if (t < ND) {
    float acc = 0.f;
    #pragma unroll
    for (int c = 0; c < 8; ++c) acc += part[c][t];
    kq_ws[b*ND + t] = acc;
  }

  // ---- theta head: Linear(387->128) -> ReLU -> Linear(128->1) ----
  if (t < ND + NHID) tin[t] = seed_ctx[b*(ND+NHID) + t];
  if (t >= ND + NHID && t < TH_IN) tin[t] = local_stats[b*3 + (t - (ND+NHID))];
  __syncthreads();
  {
    const int c = t >> 7;
    const int h = t & 127;
    const int i0 = c*49;
    const int i1 = (c == 7) ? TH_IN : i0 + 49;
    float acc = 0.f;
    for (int i = i0; i < i1; ++i) acc += tin[i] * W1[i*TH_HID + h];
    part[c][h] = acc;
  }
  __syncthreads();
  if (t < TH_HID) {
    float acc = b1[t];
    #pragma unroll
    for (int c = 0; c < 8; ++c) acc += part[c][t];
    acc = fmaxf(acc, 0.f);
    sred[t] = acc * W2[t];
  }
  __syncthreads();
  if (t < 64) {
    float v = sred[t] + sred[t + 64];
    for (int off = 32; off; off >>= 1) v += __shfl_xor(v, off);
    if (t == 0) {
      float th = v + b2[0];
      theta_ws[b] = th;
      out_theta[b] = th;
    }
  }
}

// ---- Kernel B: candm-gated rows; sparse e2c gather; deg only when e2c!=0 ----
// One wave per row, 8 rows/block. Rows with cand_mask==0 have p == +0.0 and
// hard == 0 exactly (sigmoid * 0); they skip ALL reads (x row, gather, deg).
// e2c = sum_k adj[row, cidx_k]*cval_k is an exact 0/1-integer sum; deg only
// influences the output when e2c != 0 (else the term is exactly +0.0).
__global__ __launch_bounds__(512) void row_kernel(
    const float* __restrict__ x, const float* __restrict__ adj,
    const float* __restrict__ candm,
    const float* __restrict__ kq_ws, const float* __restrict__ theta_ws,
    const int* __restrict__ cidx, const float* __restrict__ cval,
    const int* __restrict__ ccnt,
    float* __restrict__ out_hard, float* __restrict__ out_p,
    float* __restrict__ pv1, int* __restrict__ pi1,
    float* __restrict__ pv2, int* __restrict__ pi2, int* __restrict__ pcnt)
{
  const int t = threadIdx.x;
  const int wave = t >> 6, lane = t & 63;
  const int row0 = blockIdx.x * 8;
  const int b = row0 >> 11;               // 2048 rows per batch
  __shared__ float sKq[ND];
  __shared__ float sTheta; __shared__ int sK;
  __shared__ float rv[8]; __shared__ int rc[8];

  if (t < ND) sKq[t] = kq_ws[b*ND + t];
  if (t == 0) { sTheta = theta_ws[b]; sK = ccnt[b]; }
  __syncthreads();
  const int K = sK;

  const int row = row0 + wave;            // global row == b*NN + n
  const float cm = candm[row];            // wave-uniform (all lanes same addr)

  float p = 0.f;
  if (cm != 0.f) {                        // ~30% of rows; wave-uniform branch
    const float* arow = adj + (size_t)row * NN;

    // score: x[row] . kq
    const float2* x2 = (const float2*)(x + (size_t)row * ND);
    float2 xv = x2[lane];
    float sc = xv.x * sKq[2*lane] + xv.y * sKq[2*lane + 1];

    // e2c: gather K entries (lane-parallel)
    float e2c = 0.f;
    if (lane < K) e2c = arow[cidx[b*NN + lane]] * cval[b*NN + lane];
    for (int base = 64; base < K; base += 64) {
      const int k = base + lane;
      if (k < K) e2c += arow[cidx[b*NN + k]] * cval[b*NN + k];
    }

    for (int off = 32; off; off >>= 1) {
      sc  += __shfl_xor(sc, off);
      e2c += __shfl_xor(e2c, off);
    }

    float extra = 0.f;
    if (e2c != 0.f) {                     // ~4% of candidate rows
      const float4* a4 = (const float4*)arow;
      float deg = 0.f;
      #pragma unroll
      for (int k = 0; k < 8; ++k) {
        float4 a = a4[k*64 + lane];
        deg += a.x + a.y + a.z + a.w;
      }
      for (int off = 32; off; off >>= 1) deg += __shfl_xor(deg, off);
      extra = e2c / fmaxf(deg, 1.0f);
    }

    float cand = sc * 0.125f + 0.2f * extra;          // /sqrt(64) == *0.125
    p = (1.0f / (1.0f + expf(-(cand - sTheta)))) * cm;  // TAU == 1
  }

  if (lane == 0) {
    out_p[row] = p;
    out_hard[row] = (p > 0.5f) ? 1.0f : 0.0f;
    rv[wave] = p; rc[wave] = (p > 0.5f) ? 1 : 0;
  }
  __syncthreads();
  if (t == 0) {
    float V1 = -1e30f, V2 = -1e30f; int I1 = 0, I2 = 0, cnt = 0;
    #pragma unroll
    for (int w = 0; w < 8; ++w) {       // ascending n; '>' keeps lowest on ties
      float v = rv[w]; int idx = (row0 & (NN-1)) + w;
      cnt += rc[w];
      if (v > V1)      { V2=V1; I2=I1; V1=v; I1=idx; }
      else if (v > V2) { V2=v;  I2=idx; }
    }
    pv1[blockIdx.x] = V1; pi1[blockIdx.x] = I1;
    pv2[blockIdx.x] = V2; pi2[blockIdx.x] = I2;
    pcnt[blockIdx.x] = cnt;
  }
}

// ---- Kernel C: merge 256 partials per batch, trim if count > 2 --------------
__global__ __launch_bounds__(256) void trim_kernel(
    const float* __restrict__ pv1, const int* __restrict__ pi1,
    const float* __restrict__ pv2, const int* __restrict__ pi2,
    const int* __restrict__ pcnt,
    float* __restrict__ out_hard, float* __restrict__ out_p)
{
  const int b = blockIdx.x;
  const int t = threadIdx.x;
  const int g = b*256 + t;
  __shared__ int scnt[256];
  __shared__ float sv1[256]; __shared__ int si1[256];
  __shared__ float sv2[256]; __shared__ int si2[256];
  __shared__ int s_trim, s_k1, s_k2;

  scnt[t] = pcnt[g];
  sv1[t] = pv1[g]; si1[t] = pi1[g];
  sv2[t] = pv2[g]; si2[t] = pi2[g];
  __syncthreads();
  // partial t covers strictly lower n than t+s; strict '>' keeps lowest index
  for (int s = 128; s > 0; s >>= 1) {
    if (t < s) {
      scnt[t] += scnt[t+s];
      float B1 = sv1[t+s]; int Bi1 = si1[t+s];
      float B2 = sv2[t+s]; int Bi2 = si2[t+s];
      float V1 = sv1[t], V2 = sv2[t]; int I1 = si1[t], I2 = si2[t];
      if (B1 > V1)      { V2=V1; I2=I1; V1=B1; I1=Bi1; }
      else if (B1 > V2) { V2=B1; I2=Bi1; }
      if (B2 > V1)      { V2=V1; I2=I1; V1=B2; I1=Bi2; }
      else if (B2 > V2) { V2=B2; I2=Bi2; }
      sv1[t]=V1; si1[t]=I1; sv2[t]=V2; si2[t]=I2;
    }
    __syncthreads();
  }
  if (t == 0) {
    s_trim = (scnt[0] > 2) ? 1 : 0;   // over = count - (CLUSTER_SIZE_MAX-1) > 0
    s_k1 = si1[0]; s_k2 = si2[0];
  }
  __syncthreads();
  if (s_trim) {
    float* p    = out_p    + b*NN;
    float* hard = out_hard + b*NN;
    #pragma unroll
    for (int j = 0; j < 8; ++j) {
      const int nidx = j*256 + t;
      if (nidx != s_k1 && nidx != s_k2) { p[nidx] = 0.f; hard[nidx] = 0.f; }
    }
  }
}

extern "C" void kernel_launch(void* const* d_in, const int* in_sizes, int n_in,
                              void* d_out, int out_size, void* d_ws, size_t ws_size,
                              hipStream_t stream) {
  const float* x          = (const float*)d_in[0];
  const float* adj        = (const float*)d_in[1];
  const float* seed_ctx   = (const float*)d_in[2];
  const float* local_st   = (const float*)d_in[3];
  const float* cmask      = (const float*)d_in[4];
  const float* candm      = (const float*)d_in[5];
  const float* Wq         = (const float*)d_in[6];
  const float* Wk         = (const float*)d_in[7];
  const float* W1         = (const float*)d_in[8];
  const float* b1         = (const float*)d_in[9];
  const float* W2         = (const float*)d_in[10];
  const float* b2         = (const float*)d_in[11];

  float* out      = (float*)d_out;
  float* out_hard = out;                // [B,N]
  float* out_p    = out + NB*NN;        // [B,N]
  float* out_th   = out + 2*NB*NN;      // [B]

  const int NBLK = NB*NN/8;             // 2048 row-blocks
  float* ws       = (float*)d_ws;
  float* kq_ws    = ws;                       // 1024
  float* theta_ws = ws + NB*ND;               // 8
  float* pv1      = ws + NB*ND + NB;          // 2048
  float* pv2      = pv1 + NBLK;               // 2048
  int*   pi1      = (int*)(pv2 + NBLK);       // 2048
  int*   pi2      = pi1 + NBLK;               // 2048
  int*   pcnt     = pi2 + NBLK;               // 2048
  int*   cidx     = pcnt + NBLK;              // B*NN ints
  float* cval     = (float*)(cidx + NB*NN);   // B*NN floats
  int*   ccnt     = (int*)(cval + NB*NN);     // B ints

  seed_theta_kernel<<<NB, 1024, 0, stream>>>(x, seed_ctx, local_st, cmask,
                                             Wq, Wk, W1, b1, W2, b2,
                                             kq_ws, theta_ws,
                                             cidx, cval, ccnt, out_th);
  row_kernel<<<NBLK, 512, 0, stream>>>(x, adj, candm, kq_ws, theta_ws,
                                       cidx, cval, ccnt,
                                       out_hard, out_p, pv1, pi1, pv2, pi2, pcnt);
  trim_kernel<<<NB, 256, 0, stream>>>(pv1, pi1, pv2, pi2, pcnt,
                                      out_hard, out_p);
}